// Round 4
// baseline (185.476 us; speedup 1.0000x reference)
//
#include <hip/hip_runtime.h>
#include <hip/hip_bf16.h>
#include <stdint.h>

typedef __attribute__((ext_vector_type(8))) short bf16x8;
typedef __attribute__((ext_vector_type(4))) float f32x4;
typedef __attribute__((ext_vector_type(8))) unsigned short ushort8;

__device__ __forceinline__ unsigned short cvt1(float f) {
  union { __hip_bfloat16 b; unsigned short u; } v;
  v.b = __float2bfloat16(f);
  return v.u;
}

__device__ __forceinline__ void gld_lds16(const void* g, void* l) {
  __builtin_amdgcn_global_load_lds(
      (const __attribute__((address_space(1))) unsigned int*)g,
      (__attribute__((address_space(3))) unsigned int*)l,
      16, 0, 0);
}

#define FENCE() asm volatile("" ::: "memory")
#define SBAR() do { FENCE(); __builtin_amdgcn_s_barrier(); FENCE(); } while (0)

// ---------------- cast + transpose W: wt[n][k] = bf16(W[k][n]) ----------------
__global__ void cast_wt_kernel(const float* __restrict__ W,
                               unsigned short* __restrict__ wt) {
  int t = blockIdx.x * blockDim.x + threadIdx.x;  // 512*512 threads
  int n = t >> 9;
  int k = t & 511;
  wt[t] = cvt1(W[k * 512 + n]);
}

// ---------------- fused GEMM + bias + relu + LN-stats ----------------
// h = relu(x @ W + b) stored bf16; per (row, head=ntile) mean & rstd (float2).
// Tile 128x128, BK=64, 4 waves (2x2), mfma_f32_16x16x32_bf16, 4x4 frags/wave.
// A: x fp32 direct, reg-staged depth-2 + cvt + swizzled ds_write (single As buf).
// B: wt bf16 via gld_lds (pre-swizzled source), double-buffered Bs.
// Sync: raw s_barrier + counted vmcnt (never 0 mid-loop) — T3/T4 style.
// LDS tile rows stride 128B, 16B-slot XOR swizzle off(row,k8)=row*128+((k8^(row&7))*16).
__global__ __launch_bounds__(256, 2) void gemm_ln_kernel(
    const float* __restrict__ x,             // [N][512] fp32
    const unsigned short* __restrict__ wt,   // [512][512] bf16 (W^T)
    const float* __restrict__ bias,          // [512]
    unsigned short* __restrict__ h,          // [N][512] bf16
    float2* __restrict__ mr,                 // [N][4] (mean, rstd)
    int N, int mtiles) {
  __shared__ __align__(16) unsigned short As[128 * 64];
  __shared__ __align__(16) unsigned short Bs[2][128 * 64];
  __shared__ float redS[128 * 2];
  __shared__ float redQ[128 * 2];

  // ---- XCD-grouped bid remap: 4 ntile-peers of an mtile share bid%8 ----
  const int nfull = (mtiles >> 3) << 3;
  const int full_bids = nfull * 4;
  int mtile, ntile;
  {
    const int bid = blockIdx.x;
    if (bid < full_bids) {
      const int chunk = bid >> 5, j = bid & 31;
      mtile = (chunk << 3) + (j & 7);
      ntile = j >> 3;
    } else {
      const int j = bid - full_bids;
      const int rem = mtiles - nfull;
      mtile = nfull + j % rem;
      ntile = j / rem;
    }
  }
  const int m0 = mtile << 7;
  const int n0 = ntile << 7;

  const int tid = threadIdx.x;
  const int lane = tid & 63;
  const int wid = tid >> 6;
  const int wr = wid >> 1;
  const int wc = wid & 1;

  f32x4 acc[4][4];
#pragma unroll
  for (int m = 0; m < 4; m++)
#pragma unroll
    for (int n = 0; n < 4; n++) acc[m][n] = (f32x4){0.f, 0.f, 0.f, 0.f};

  char* AsB = (char*)As;

  // ---- A staging geometry: 4 its x 8 fp32/thread ----
  const float* aBase[4];
  int aDst[4];
#pragma unroll
  for (int it = 0; it < 4; it++) {
    const int id = it * 256 + tid;   // [0,1024)
    const int row = id >> 3;         // [0,128)
    const int k8 = id & 7;
    aBase[it] = x + (long)min(m0 + row, N - 1) * 512 + k8 * 8;
    aDst[it] = row * 128 + ((k8 ^ (row & 7)) << 4);
  }

  // ---- B staging geometry (gld_lds, pre-swizzled source): 4 lines ----
  const unsigned short* bP[4];
  int bLds[4];
#pragma unroll
  for (int L = 0; L < 4; L++) {
    const int p = (L << 12) + tid * 16;
    const int row = p >> 7;
    const int slot = (p >> 4) & 7;
    const int k8 = slot ^ (row & 7);
    bP[L] = wt + (long)(n0 + row) * 512 + k8 * 8;
    bLds[L] = (L << 12) + (wid << 10);
  }

  // ---- fragment read offsets (swizzled) ----
  const int rsel = lane & 15;
  const int k8l = lane >> 4;
  int offA[2][4], offB[2][4];
#pragma unroll
  for (int kk = 0; kk < 2; kk++)
#pragma unroll
    for (int m = 0; m < 4; m++) {
      const int ra = wr * 64 + m * 16 + rsel;
      offA[kk][m] = ra * 128 + ((((kk << 2) + k8l) ^ (ra & 7)) << 4);
      const int rb = wc * 64 + m * 16 + rsel;
      offB[kk][m] = rb * 128 + ((((kk << 2) + k8l) ^ (rb & 7)) << 4);
    }

  float4 ar[2][4][2];

#define ISSUE_A(buf, tt)                                        \
  {                                                             \
    _Pragma("unroll") for (int it = 0; it < 4; it++) {          \
      const float4* ap = (const float4*)(aBase[it] + ((tt) << 6)); \
      ar[buf][it][0] = ap[0];                                   \
      ar[buf][it][1] = ap[1];                                   \
    }                                                           \
  }

#define ISSUE_B(dbuf, tt)                                       \
  {                                                             \
    _Pragma("unroll") for (int L = 0; L < 4; L++)               \
        gld_lds16(bP[L] + ((tt) << 6), (char*)Bs[dbuf] + bLds[L]); \
  }

#define CVT_WRITE(buf)                                          \
  {                                                             \
    ushort8 o[4];                                               \
    _Pragma("unroll") for (int it = 0; it < 4; it++) {          \
      o[it][0] = cvt1(ar[buf][it][0].x);                        \
      o[it][1] = cvt1(ar[buf][it][0].y);                        \
      o[it][2] = cvt1(ar[buf][it][0].z);                        \
      o[it][3] = cvt1(ar[buf][it][0].w);                        \
      o[it][4] = cvt1(ar[buf][it][1].x);                        \
      o[it][5] = cvt1(ar[buf][it][1].y);                        \
      o[it][6] = cvt1(ar[buf][it][1].z);                        \
      o[it][7] = cvt1(ar[buf][it][1].w);                        \
    }                                                           \
    _Pragma("unroll") for (int it = 0; it < 4; it++)            \
        *(ushort8*)(AsB + aDst[it]) = o[it];                    \
  }

  // ---- prologue: queue = [A0:8, A1:8, B0:4, B1:4] ----
  ISSUE_A(0, 0);
  FENCE();
  ISSUE_A(1, 1);
  FENCE();
  ISSUE_B(0, 0);
  FENCE();
  ISSUE_B(1, 1);
  asm volatile("s_waitcnt vmcnt(16)" ::: "memory");  // A0 arrived
  __builtin_amdgcn_sched_barrier(0);
  CVT_WRITE(0);
  asm volatile("s_waitcnt vmcnt(4)" ::: "memory");   // A1,B0 arrived (B1 in flight)
  asm volatile("s_waitcnt lgkmcnt(0)" ::: "memory");
  __builtin_amdgcn_sched_barrier(0);
  SBAR();  // As=A(0) visible, Bs[0]=B(0) ready

#pragma unroll
  for (int t = 0; t < 8; ++t) {
    if (t < 6) {
      ISSUE_A(t & 1, t + 2);  // ar[t&1] free: A(t) was cvt'd last iter
      FENCE();
    }
    // ---- MFMA(t): As = A(t), Bs[t&1] = B(t) ----
    {
      const char* BsB = (const char*)Bs[t & 1];
#pragma unroll
      for (int kk = 0; kk < 2; kk++) {
        bf16x8 af[4], bq[4];
#pragma unroll
        for (int m = 0; m < 4; m++) af[m] = *(const bf16x8*)(AsB + offA[kk][m]);
#pragma unroll
        for (int n = 0; n < 4; n++) bq[n] = *(const bf16x8*)(BsB + offB[kk][n]);
#pragma unroll
        for (int m = 0; m < 4; m++)
#pragma unroll
          for (int n = 0; n < 4; n++)
            acc[m][n] = __builtin_amdgcn_mfma_f32_16x16x32_bf16(
                af[m], bq[n], acc[m][n], 0, 0, 0);
      }
    }
    if (t < 7) {
      // retire A(t+1)+B(t+1); keep A(t+2) (8 ops) in flight. t==6: nothing newer.
      if (t == 6) asm volatile("s_waitcnt vmcnt(0)" ::: "memory");
      else        asm volatile("s_waitcnt vmcnt(8)" ::: "memory");
      __builtin_amdgcn_sched_barrier(0);
      SBAR();  // #1: all waves done reading As (frag reads retired pre-MFMA)
      CVT_WRITE((t + 1) & 1);  // As <- A(t+1)
      if (t < 6) {
        FENCE();
        ISSUE_B(t & 1, t + 2);  // Bs[t&1] readers all passed barrier #1
      }
      asm volatile("s_waitcnt lgkmcnt(0)" ::: "memory");
      __builtin_amdgcn_sched_barrier(0);
      SBAR();  // #2: As=A(t+1) visible to all; Bs[(t+1)&1]=B(t+1) ready
    }
  }

  // ---- epilogue: bias + relu, store h bf16, per-row sum/sumsq ----
  const int colb = n0 + wc * 64 + rsel;
  float bval[4];
#pragma unroll
  for (int n = 0; n < 4; n++) bval[n] = bias[colb + n * 16];

#pragma unroll
  for (int m = 0; m < 4; m++) {
    const int rbase = wr * 64 + m * 16 + ((lane >> 4) << 2);
#pragma unroll
    for (int i = 0; i < 4; i++) {
      const int row_l = rbase + i;
      const long row_g = (long)m0 + row_l;
      const bool valid = row_g < N;
      float s = 0.f, q = 0.f;
#pragma unroll
      for (int n = 0; n < 4; n++) {
        float v = acc[m][n][i] + bval[n];
        v = fmaxf(v, 0.f);
        s += v;
        q += v * v;
        if (valid) h[row_g * 512 + colb + n * 16] = cvt1(v);
      }
#pragma unroll
      for (int d = 1; d < 16; d <<= 1) {
        s += __shfl_xor(s, d, 64);
        q += __shfl_xor(q, d, 64);
      }
      if (rsel == 0) {
        redS[row_l * 2 + wc] = s;
        redQ[row_l * 2 + wc] = q;
      }
    }
  }
  __syncthreads();
  if (tid < 128) {
    const long row_g = (long)m0 + tid;
    if (row_g < N) {
      float s = redS[tid * 2] + redS[tid * 2 + 1];
      float q = redQ[tid * 2] + redQ[tid * 2 + 1];
      float mean = s * (1.f / 128.f);
      float var = q * (1.f / 128.f) - mean * mean;
      mr[row_g * 4 + ntile] = make_float2(mean, rsqrtf(var + 1e-5f));
    }
  }
}

// ---------------- per-graph online segment softmax + weighted pooling ----------------
__global__ __launch_bounds__(512) void pool_kernel(
    const unsigned short* __restrict__ h, const float2* __restrict__ mr,
    const float* __restrict__ qs, const int* __restrict__ gidx,
    float* __restrict__ out, int N) {
  const int g = blockIdx.x;
  const int ch = threadIdx.x;

  int lo = 0, hi = N;
  while (lo < hi) {
    int mid = (lo + hi) >> 1;
    if (gidx[mid] < g) lo = mid + 1; else hi = mid;
  }
  const int s0 = lo;
  hi = N;
  while (lo < hi) {
    int mid = (lo + hi) >> 1;
    if (gidx[mid] < g + 1) lo = mid + 1; else hi = mid;
  }
  const int e0 = lo;

  const float qscale = qs[ch];
  const int head = ch >> 7;
  float m = -INFINITY, S = 0.f, Nm = 0.f;

  int n = s0;
  for (; n + 4 <= e0; n += 4) {
    float hv[4];
    float2 mv[4];
#pragma unroll
    for (int j = 0; j < 4; j++) {
      hv[j] = __uint_as_float((unsigned int)h[(long)(n + j) * 512 + ch] << 16);
      mv[j] = mr[(long)(n + j) * 4 + head];
    }
#pragma unroll
    for (int j = 0; j < 4; j++) {
      float qv = (hv[j] - mv[j].x) * mv[j].y * qscale;
      float nm = fmaxf(m, qv);
      float c = __expf(m - nm);
      float p = __expf(qv - nm);
      S = S * c + p;
      Nm = Nm * c + p * hv[j];
      m = nm;
    }
  }
  for (; n < e0; ++n) {
    float hv = __uint_as_float((unsigned int)h[(long)n * 512 + ch] << 16);
    float2 mv = mr[(long)n * 4 + head];
    float qv = (hv - mv.x) * mv.y * qscale;
    float nm = fmaxf(m, qv);
    float c = __expf(m - nm);
    float p = __expf(qv - nm);
    S = S * c + p;
    Nm = Nm * c + p * hv;
    m = nm;
  }
  out[g * 512 + ch] = Nm / (S + 1e-16f);
}

extern "C" void kernel_launch(void* const* d_in, const int* in_sizes, int n_in,
                              void* d_out, int out_size, void* d_ws, size_t ws_size,
                              hipStream_t stream) {
  const float* x = (const float*)d_in[0];
  const float* W = (const float*)d_in[1];
  const float* bias = (const float*)d_in[2];
  const float* qs = (const float*)d_in[3];
  const int* gidx = (const int*)d_in[4];
  const int N = in_sizes[0] / 512;
  const int B = out_size / 512;
  float* out = (float*)d_out;

  char* ws = (char*)d_ws;
  size_t off = 0;
  auto alloc = [&](size_t bytes) {
    char* p = ws + off;
    off += (bytes + 255) & ~(size_t)255;
    return p;
  };
  unsigned short* wt = (unsigned short*)alloc((size_t)512 * 512 * 2);
  unsigned short* h = (unsigned short*)alloc((size_t)N * 512 * 2);
  float2* mr = (float2*)alloc((size_t)N * 4 * sizeof(float2));
  (void)ws_size;  // need ~106 MB

  cast_wt_kernel<<<(512 * 512) / 256, 256, 0, stream>>>(W, wt);
  const int mtiles = (N + 127) / 128;
  gemm_ln_kernel<<<mtiles * 4, 256, 0, stream>>>(x, wt, bias, h, mr, N, mtiles);
  pool_kernel<<<B, 512, 0, stream>>>(h, mr, qs, gidx, out, N);
}